// Round 1
// baseline (154.880 us; speedup 1.0000x reference)
//
#include <hip/hip_runtime.h>
#include <hip/hip_bf16.h>

typedef __attribute__((ext_vector_type(8))) short  bf16x8;
typedef __attribute__((ext_vector_type(4))) float  f32x4;
typedef __attribute__((ext_vector_type(4))) int    i32x4;

#define B_   8
#define R_   4
#define N_   2048
#define S_   6
#define DIN  32
#define DOUT 32

// ---------------------------------------------------------------------------
// Pre-kernel: XW_T[b][r][e][m] = bf16( coef[r] * sum_d X[b,r,m,d] * fc_w[r,d,e] )
// coef[r] = sum_s theta[r,s]*t[r,s].  Stored transposed ([e][m]) so the main
// kernel's MFMA B-fragment is one contiguous 16B load per lane.
// ---------------------------------------------------------------------------
__global__ __launch_bounds__(256) void prep_xw(
    const float* __restrict__ theta, const float* __restrict__ tpar,
    const float* __restrict__ X,     const float* __restrict__ fcw,
    __hip_bfloat16* __restrict__ xwt)
{
    int br    = blockIdx.x >> 5;      // b*4 + r   (32 of them)
    int mtile = blockIdx.x & 31;      // N/64 = 32 m-tiles
    int r     = br & 3;
    int t     = threadIdx.x;
    int m     = mtile * 64 + (t & 63);
    int egrp  = t >> 6;               // 0..3

    float coef = 0.f;
#pragma unroll
    for (int s = 0; s < S_; ++s) coef += theta[r * S_ + s] * tpar[r * S_ + s];

    const float* xrow = X + ((size_t)br * N_ + m) * DIN;
    float xr[DIN];
#pragma unroll
    for (int i = 0; i < DIN / 4; ++i) {
        f32x4 v = *(const f32x4*)(xrow + i * 4);
        xr[i * 4 + 0] = v.x; xr[i * 4 + 1] = v.y;
        xr[i * 4 + 2] = v.z; xr[i * 4 + 3] = v.w;
    }
#pragma unroll
    for (int eb = 0; eb < 8; ++eb) {
        int e = egrp * 8 + eb;
        float acc = 0.f;
#pragma unroll
        for (int d = 0; d < DIN; ++d) acc += xr[d] * fcw[(r * DIN + d) * DOUT + e];
        xwt[((size_t)br * DOUT + e) * N_ + m] = __float2bfloat16(coef * acc);
    }
}

// ---------------------------------------------------------------------------
// Main fused kernel: per (b, 16-row n-tile) block, 4 waves (one per relation).
//   acc = A(bf16) x XW_T(bf16) via mfma_f32_16x16x32_bf16, K=2048
//   epilogue: +fc_b, prelu0, 4x4 conv mix across r (LDS), +conv_b, prelu1.
// ---------------------------------------------------------------------------
__global__ __launch_bounds__(256) void fused_main(
    const float* __restrict__ A,   const __hip_bfloat16* __restrict__ xwt,
    const float* __restrict__ fcb, const float* __restrict__ cw,
    const float* __restrict__ cb,  const float* __restrict__ p0p,
    const float* __restrict__ p1p, float* __restrict__ out)
{
    __shared__ float hlds[R_][16][DOUT + 1];   // +1 pad: bank-conflict-free

    int b    = blockIdx.x >> 7;     // 8 batches
    int tile = blockIdx.x & 127;    // 128 n-tiles of 16
    int n0   = tile * 16;
    int t    = threadIdx.x;
    int r    = t >> 6;              // wave = relation
    int l    = t & 63;
    int row16 = l & 15;             // M row within tile (A frag), e col (B frag)
    int kg    = l >> 4;             // k-group 0..3

    const float*  Ap  = A + (((size_t)(b * R_ + r)) * N_ + (n0 + row16)) * N_ + kg * 8;
    const ushort* xw  = (const ushort*)xwt + ((size_t)(b * R_ + r) * DOUT) * N_;
    const ushort* xw0 = xw + (size_t)row16 * N_        + kg * 8;
    const ushort* xw1 = xw + (size_t)(16 + row16) * N_ + kg * 8;

    f32x4 acc0 = {0.f, 0.f, 0.f, 0.f};
    f32x4 acc1 = {0.f, 0.f, 0.f, 0.f};

#pragma unroll 4
    for (int kt = 0; kt < N_ / 32; ++kt) {
        f32x4 a0 = *(const f32x4*)(Ap + kt * 32);
        f32x4 a1 = *(const f32x4*)(Ap + kt * 32 + 4);
        i32x4 bv0 = *(const i32x4*)(xw0 + kt * 32);
        i32x4 bv1 = *(const i32x4*)(xw1 + kt * 32);
        i32x4 av;
        asm("v_cvt_pk_bf16_f32 %0, %1, %2" : "=v"(av.x) : "v"(a0.x), "v"(a0.y));
        asm("v_cvt_pk_bf16_f32 %0, %1, %2" : "=v"(av.y) : "v"(a0.z), "v"(a0.w));
        asm("v_cvt_pk_bf16_f32 %0, %1, %2" : "=v"(av.z) : "v"(a1.x), "v"(a1.y));
        asm("v_cvt_pk_bf16_f32 %0, %1, %2" : "=v"(av.w) : "v"(a1.z), "v"(a1.w));
        bf16x8 af = __builtin_bit_cast(bf16x8, av);
        bf16x8 b0 = __builtin_bit_cast(bf16x8, bv0);
        bf16x8 b1 = __builtin_bit_cast(bf16x8, bv1);
        acc0 = __builtin_amdgcn_mfma_f32_16x16x32_bf16(af, b0, acc0, 0, 0, 0);
        acc1 = __builtin_amdgcn_mfma_f32_16x16x32_bf16(af, b1, acc1, 0, 0, 0);
    }

    float p0 = p0p[0], p1 = p1p[0];

    // fc bias + prelu0 -> LDS  (C layout: row = kg*4+j, col = row16 / 16+row16)
#pragma unroll
    for (int j = 0; j < 4; ++j) {
        int rw = kg * 4 + j;
        float v0 = acc0[j] + fcb[r * DOUT + row16];
        float v1 = acc1[j] + fcb[r * DOUT + 16 + row16];
        hlds[r][rw][row16]      = v0 >= 0.f ? v0 : p0 * v0;
        hlds[r][rw][16 + row16] = v1 >= 0.f ? v1 : p0 * v1;
    }
    __syncthreads();

    // conv mix across relations: wave r produces output channel q = r
    int q = r;
    float c0 = cw[q * R_ + 0], c1 = cw[q * R_ + 1];
    float c2 = cw[q * R_ + 2], c3 = cw[q * R_ + 3];
    float cbq = cb[q];
    int e  = l & 31;
    int rg = l >> 5;
#pragma unroll
    for (int i = 0; i < 8; ++i) {
        int row = rg * 8 + i;
        float mx = cbq + c0 * hlds[0][row][e] + c1 * hlds[1][row][e]
                       + c2 * hlds[2][row][e] + c3 * hlds[3][row][e];
        float lat = mx >= 0.f ? mx : p1 * mx;
        out[(((size_t)b * R_ + q) * N_ + (n0 + row)) * DOUT + e] = lat;
    }
}

extern "C" void kernel_launch(void* const* d_in, const int* in_sizes, int n_in,
                              void* d_out, int out_size, void* d_ws, size_t ws_size,
                              hipStream_t stream)
{
    const float* theta = (const float*)d_in[0];
    const float* tpar  = (const float*)d_in[1];
    const float* A     = (const float*)d_in[2];
    const float* X     = (const float*)d_in[3];
    const float* fcw   = (const float*)d_in[4];
    const float* fcb   = (const float*)d_in[5];
    const float* cw    = (const float*)d_in[6];
    const float* cb    = (const float*)d_in[7];
    const float* p0    = (const float*)d_in[8];
    const float* p1    = (const float*)d_in[9];

    __hip_bfloat16* xwt = (__hip_bfloat16*)d_ws;   // 8*4*32*2048*2B = 4 MiB

    prep_xw<<<B_ * R_ * (N_ / 64), 256, 0, stream>>>(theta, tpar, X, fcw, xwt);
    fused_main<<<B_ * (N_ / 16), 256, 0, stream>>>(A, xwt, fcb, cw, cb, p0, p1,
                                                   (float*)d_out);
}